// Round 6
// baseline (457.212 us; speedup 1.0000x reference)
//
#include <hip/hip_runtime.h>
#include <stdint.h>

// ---------- helpers ----------
typedef short v8s __attribute__((ext_vector_type(8)));
typedef float v4f __attribute__((ext_vector_type(4)));
typedef float v2f __attribute__((ext_vector_type(2)));

#define MAXDEG 64    // Poisson(16) tail: P(deg>64) ~ 5e-19/node -> safe for fixed graph
#define CSTRIDE 16   // one counter per 64B line (measured -6us on the atomic phase)

__device__ inline unsigned short f2bf(float f) {
    union { float f; unsigned u; } c; c.f = f;
    unsigned u = c.u;
    unsigned r = (u + 0x7FFFu + ((u >> 16) & 1u)) >> 16;  // RNE
    return (unsigned short)r;
}
__device__ inline void gl_lds16(const unsigned short* g, unsigned short* l) {
    __builtin_amdgcn_global_load_lds(
        (const __attribute__((address_space(1))) unsigned int*)(g),
        (__attribute__((address_space(3))) unsigned int*)(l), 16, 0, 0);
}
__device__ inline v8s cvt8(float4 a, float4 b) {  // 8 f32 -> 8 bf16 (same bits as f2bf)
    v8s r;
    r[0] = (short)f2bf(a.x); r[1] = (short)f2bf(a.y);
    r[2] = (short)f2bf(a.z); r[3] = (short)f2bf(a.w);
    r[4] = (short)f2bf(b.x); r[5] = (short)f2bf(b.y);
    r[6] = (short)f2bf(b.z); r[7] = (short)f2bf(b.w);
    return r;
}

// ---------- k_pre0: zero counters + W transpose + zero bufA pad rows ----------
__global__ void k_pre0(int* __restrict__ cnt, int zTotal,
                       const float* __restrict__ W1, const float* __restrict__ W2,
                       const float* __restrict__ W3, unsigned short* __restrict__ Wt,
                       int gZ, int gW, int* __restrict__ apad, int padTotal) {
    int b = blockIdx.x;
    if (b < gZ) {
        int idx = b * 256 + threadIdx.x;   // int4 granularity
        if (idx < zTotal) ((int4*)cnt)[idx] = make_int4(0, 0, 0, 0);
    } else if (b < gZ + gW) {
        int idx = (b - gZ) * 256 + threadIdx.x;  // < 163840 exact
        const float* W; int base, N;
        if (idx < 65536)       { W = W1; base = 0;      N = 256; }
        else if (idx < 131072) { W = W2; base = 65536;  N = 256; }
        else                   { W = W3; base = 131072; N = 128; }
        int loc = idx - base;
        int nn = loc >> 8;   // K = 256
        int k = loc & 255;
        Wt[idx] = f2bf(W[(size_t)k * N + nn]);
    } else {
        int idx = (b - gZ - gW) * 256 + threadIdx.x;  // int4 granularity
        if (idx < padTotal) ((int4*)apad)[idx] = make_int4(0, 0, 0, 0);
    }
}

// ---------- GEMM body: Hs[m,n] = s(m) * sum_k A[m,k] * W[k,n] ----------
// CONVA: A read from f32 x, converted in-register during staging (no bufA round trip).
// SCALE: s = rsqrt(cnt[m]+1); else s = 1 for valid rows (pad rows always 0).
template <bool CONVA, bool SCALE>
__device__ inline void gemm_body(int bm, int bn,
                                 const float* __restrict__ Af,
                                 const unsigned short* __restrict__ Ab,
                                 const unsigned short* __restrict__ Wt,
                                 unsigned short* __restrict__ Hs,
                                 const int* __restrict__ cnt, int n, int N) {
    __shared__ unsigned short sA[128 * 32];
    __shared__ unsigned short sB[128 * 32];
    const int t = threadIdx.x;
    const int lane = t & 63;
    const int wave = t >> 6;
    const int wm = wave >> 1, wn = wave & 1;
    const int m0 = bm * 128;
    const int n0 = bn * 128;

    v4f acc[4][4];
#pragma unroll
    for (int i = 0; i < 4; i++)
#pragma unroll
        for (int j = 0; j < 4; j++)
#pragma unroll
            for (int r = 0; r < 4; r++) acc[i][j][r] = 0.f;

    const int c0 = t, c1 = t + 256;
    const int r0 = c0 >> 2, kc0 = (c0 & 3) * 8;
    const int r1 = c1 >> 2, kc1 = (c1 & 3) * 8;
    const size_t aBase0 = (size_t)(m0 + r0) * 256 + kc0;
    const size_t aBase1 = (size_t)(m0 + r1) * 256 + kc1;
    const size_t bBase0 = (size_t)(n0 + r0) * 256 + kc0;
    const size_t bBase1 = (size_t)(n0 + r1) * 256 + kc1;

    const int q = lane >> 4;
    const int lm = lane & 15;

    for (int k0 = 0; k0 < 256; k0 += 32) {
        __syncthreads();
        if constexpr (CONVA) {
            float4 u0, u1, u2, u3;
            if (m0 + r0 < n) {
                u0 = *(const float4*)&Af[aBase0 + k0];
                u1 = *(const float4*)&Af[aBase0 + k0 + 4];
            } else { u0 = make_float4(0.f,0.f,0.f,0.f); u1 = u0; }
            if (m0 + r1 < n) {
                u2 = *(const float4*)&Af[aBase1 + k0];
                u3 = *(const float4*)&Af[aBase1 + k0 + 4];
            } else { u2 = make_float4(0.f,0.f,0.f,0.f); u3 = u2; }
            *(v8s*)&sA[c0 * 8] = cvt8(u0, u1);
            *(v8s*)&sA[c1 * 8] = cvt8(u2, u3);
        } else {
            gl_lds16(Ab + aBase0 + k0, &sA[c0 * 8]);
            gl_lds16(Ab + aBase1 + k0, &sA[c1 * 8]);
        }
        gl_lds16(Wt + bBase0 + k0, &sB[c0 * 8]);
        gl_lds16(Wt + bBase1 + k0, &sB[c1 * 8]);
        __syncthreads();

        v8s afr[4], bfr[4];
#pragma unroll
        for (int i = 0; i < 4; i++) {
            int r = wm * 64 + i * 16 + lm;
            afr[i] = *(const v8s*)&sA[r * 32 + q * 8];
        }
#pragma unroll
        for (int j = 0; j < 4; j++) {
            int nn = wn * 64 + j * 16 + lm;
            bfr[j] = *(const v8s*)&sB[nn * 32 + q * 8];
        }
#pragma unroll
        for (int i = 0; i < 4; i++)
#pragma unroll
            for (int j = 0; j < 4; j++)
                acc[i][j] = __builtin_amdgcn_mfma_f32_16x16x32_bf16(afr[i], bfr[j],
                                                                    acc[i][j], 0, 0, 0);
    }

    // epilogue: C/D layout col=lane&15, row=(lane>>4)*4+reg
#pragma unroll
    for (int i = 0; i < 4; i++) {
        int mbase = m0 + wm * 64 + i * 16 + q * 4;
#pragma unroll
        for (int r = 0; r < 4; r++) {
            int m = mbase + r;
            float s;
            if constexpr (SCALE)
                s = (m < n) ? rsqrtf((float)(cnt[(size_t)m * CSTRIDE] + 1)) : 0.f;
            else
                s = (m < n) ? 1.f : 0.f;
#pragma unroll
            for (int j = 0; j < 4; j++) {
                int colI = n0 + wn * 64 + j * 16 + lm;
                Hs[(size_t)m * N + colI] = f2bf(acc[i][j][r] * s);
            }
        }
    }
}

// ---------- fused: edge bucket-scatter (atomic service wall) + GEMM1 hidden under it --
// blocks [0,gEdge): p = atomicAdd(cnt[dst]); col[dst*64+p] = src. Independent of gemm.
// blocks [gEdge,..): gemm1, A self-converted from f32 x, NOSCALE (no cnt dependence).
__launch_bounds__(256, 4)
__global__ void k_fused(const int* __restrict__ src, const int* __restrict__ dst, int E,
                        int* __restrict__ cnt, int* __restrict__ col,
                        const float* __restrict__ x, const unsigned short* __restrict__ W1t,
                        unsigned short* __restrict__ Hs, int n, int gEdge) {
    int b = blockIdx.x;
    if (b < gEdge) {
        int e = b * 256 + threadIdx.x;
        if (e < E) {
            int d = dst[e];
            int p = atomicAdd(&cnt[(size_t)d * CSTRIDE], 1);
            if (p < MAXDEG) col[(size_t)d * MAXDEG + p] = src[e];
        }
    } else {
        int bx = b - gEdge;
        gemm_body<true, false>(bx >> 1, bx & 1, x, nullptr, W1t, Hs, nullptr, n, 256);
    }
}

template <bool SCALE>
__launch_bounds__(256, 4)
__global__ void k_gemm(const unsigned short* __restrict__ A,
                       const unsigned short* __restrict__ Wt,
                       unsigned short* __restrict__ Hs,
                       const int* __restrict__ cnt, int n, int N) {
    gemm_body<false, SCALE>(blockIdx.x, blockIdx.y, nullptr, A, Wt, Hs, cnt, n, N);
}

// ---------- aggregation ----------
// NSCALE: Hs rows are UNSCALED h; per-row scale dinv[c]=rsqrt(cnt[c]+1) computed ONCE
// per 64-chunk as a per-lane load+rsqrt (1 extra load instr / 64 rows), broadcast to the
// quad loop via __shfl (LDS pipe, no vmem slot). Round-5 lesson: per-row scalar gathers
// doubled load-instruction count on a request-slot-limited kernel -> 2.1x slowdown.
// Channel-split (CS<D) halves per-phase gather working set (measured win for D=256).
// 4-deep gather ILP + 1-deep tail (round-2 proven form). Packed-f32 accumulate.
template <int D, int CS, bool RELU, bool F32OUT, bool NSCALE>
__launch_bounds__(256, 8)
__global__ void k_agg(const unsigned short* __restrict__ Hs,
                      const int* __restrict__ cnt, const int* __restrict__ col,
                      const float* __restrict__ bias,
                      unsigned short* __restrict__ outb, float* __restrict__ outf,
                      int n, int nzero) {
    constexpr int LPN = CS / 8;    // lanes per neighbor row (16 for CS=128)
    constexpr int NPG = 64 / LPN;  // neighbors per gather instruction (4)
    const int lane = threadIdx.x & 63;
    const int i = blockIdx.x * 4 + (threadIdx.x >> 6);
    const int ch0 = blockIdx.y * CS;   // channel slice base
    if (i >= n) return;
    const int g = lane / LPN;      // neighbor slot within the gather
    const int cl = lane % LPN;     // channel chunk (8 channels each)

    v2f acc[4];
#pragma unroll
    for (int k = 0; k < 4; k++) acc[k] = (v2f){0.f, 0.f};

    // unpack bf16 pair as bit-ops -> packed f32 (lo = u<<16, hi = u&0xffff0000)
    auto accq = [&](unsigned u, int k, float s) {
        union { unsigned uu; float f; } lo, hi;
        lo.uu = u << 16;
        hi.uu = u & 0xffff0000u;
        if constexpr (NSCALE) {
            acc[k][0] += lo.f * s;
            acc[k][1] += hi.f * s;
        } else {
            v2f t; t[0] = lo.f; t[1] = hi.f;
            acc[k] += t;
        }
    };
    auto acc16 = [&](uint4 q, float s) {
        accq(q.x, 0, s); accq(q.y, 1, s); accq(q.z, 2, s); accq(q.w, 3, s);
    };

    const unsigned short* base = Hs + ch0 + cl * 8;
    const int deg = cnt[(size_t)i * CSTRIDE];
    const size_t cbase = (size_t)i * MAXDEG;
    const int T = deg + 1;                       // self + neighbors
    const int Tpad = (T + NPG - 1) & ~(NPG - 1); // pad with zero-row nzero

    for (int b = 0; b < Tpad; b += 64) {
        int t = b + lane;
        int v;
        if (t == 0) v = i;                        // self loop
        else if (t <= deg) v = col[cbase + t - 1];  // padded bucket load
        else v = nzero;                           // zero row pad (cnt[nzero]=0 -> dv=1)
        float dv = 0.f;
        if constexpr (NSCALE)
            dv = rsqrtf((float)(cnt[(size_t)v * CSTRIDE] + 1));
        int lim = min(64, Tpad - b);
        int t2 = 0;
        for (; t2 + 4 * NPG <= lim; t2 += 4 * NPG) {
            int c0 = __shfl(v, t2 + 0 * NPG + g);
            int c1 = __shfl(v, t2 + 1 * NPG + g);
            int c2 = __shfl(v, t2 + 2 * NPG + g);
            int c3 = __shfl(v, t2 + 3 * NPG + g);
            float s0 = 0.f, s1 = 0.f, s2 = 0.f, s3 = 0.f;
            if constexpr (NSCALE) {
                s0 = __shfl(dv, t2 + 0 * NPG + g);
                s1 = __shfl(dv, t2 + 1 * NPG + g);
                s2 = __shfl(dv, t2 + 2 * NPG + g);
                s3 = __shfl(dv, t2 + 3 * NPG + g);
            }
            uint4 q0 = *(const uint4*)(base + (size_t)c0 * D);
            uint4 q1 = *(const uint4*)(base + (size_t)c1 * D);
            uint4 q2 = *(const uint4*)(base + (size_t)c2 * D);
            uint4 q3 = *(const uint4*)(base + (size_t)c3 * D);
            acc16(q0, s0); acc16(q1, s1); acc16(q2, s2); acc16(q3, s3);
        }
        for (; t2 + NPG <= lim; t2 += NPG) {
            int c0 = __shfl(v, t2 + g);
            float s0 = 0.f;
            if constexpr (NSCALE) s0 = __shfl(dv, t2 + g);
            uint4 q0 = *(const uint4*)(base + (size_t)c0 * D);
            acc16(q0, s0);
        }
    }

    // reduce across neighbor slots
#pragma unroll
    for (int off = LPN; off < 64; off <<= 1) {
#pragma unroll
        for (int k = 0; k < 4; k++) {
            acc[k][0] += __shfl_xor(acc[k][0], off);
            acc[k][1] += __shfl_xor(acc[k][1], off);
        }
    }

    if (g == 0) {  // lanes 0..LPN-1 write
        float di = rsqrtf((float)(deg + 1));
        float o[8];
#pragma unroll
        for (int k = 0; k < 4; k++) {
            o[2 * k + 0] = di * acc[k][0] + bias[ch0 + cl * 8 + 2 * k + 0];
            o[2 * k + 1] = di * acc[k][1] + bias[ch0 + cl * 8 + 2 * k + 1];
        }
        if (RELU) {
#pragma unroll
            for (int k = 0; k < 8; k++) o[k] = fmaxf(o[k], 0.f);
        }
        if constexpr (F32OUT) {
            float* p = outf + (size_t)i * D + ch0 + cl * 8;
            *(float4*)p = make_float4(o[0], o[1], o[2], o[3]);
            *(float4*)(p + 4) = make_float4(o[4], o[5], o[6], o[7]);
        } else {
            uint4 q;
            q.x = ((unsigned)f2bf(o[1]) << 16) | f2bf(o[0]);
            q.y = ((unsigned)f2bf(o[3]) << 16) | f2bf(o[2]);
            q.z = ((unsigned)f2bf(o[5]) << 16) | f2bf(o[4]);
            q.w = ((unsigned)f2bf(o[7]) << 16) | f2bf(o[6]);
            *(uint4*)(outb + (size_t)i * D + ch0 + cl * 8) = q;
        }
    }
}

// ---------- launch ----------
extern "C" void kernel_launch(void* const* d_in, const int* in_sizes, int n_in,
                              void* d_out, int out_size, void* d_ws, size_t ws_size,
                              hipStream_t stream) {
    const float* x  = (const float*)d_in[0];
    const int*   ei = (const int*)d_in[1];   // [2, E] int32
    const float* W1 = (const float*)d_in[2];
    const float* b1 = (const float*)d_in[3];
    const float* W2 = (const float*)d_in[4];
    const float* b2 = (const float*)d_in[5];
    const float* W3 = (const float*)d_in[6];
    const float* b3 = (const float*)d_in[7];

    const int n = in_sizes[0] / 256;     // 50000
    const int E = in_sizes[1] / 2;       // 800000
    const int mpad = ((n + 127) / 128) * 128;  // 50048

    char* ws = (char*)d_ws;
    size_t off = 0;
    auto alloc = [&](size_t bytes) -> void* {
        void* p = ws + off;
        off += (bytes + 255) & ~(size_t)255;
        return p;
    };
    int* cnt      = (int*)alloc((size_t)mpad * CSTRIDE * 4);  // padded counters, 3.2MB
    int* col      = (int*)alloc((size_t)n * MAXDEG * 4);      // padded buckets, 12.8MB
    unsigned short* Wt = (unsigned short*)alloc((size_t)163840 * 2);
    unsigned short* W1t = Wt;
    unsigned short* W2t = Wt + 65536;
    unsigned short* W3t = Wt + 131072;
    unsigned short* bufA = (unsigned short*)alloc((size_t)mpad * 256 * 2);
    unsigned short* bufB = (unsigned short*)alloc((size_t)mpad * 256 * 2);
    (void)ws_size; (void)n_in; (void)out_size;

    const int* srcp = ei;
    const int* dstp = ei + E;
    const int zTotal = mpad * CSTRIDE / 4;           // int4 stores to zero ALL of cnt
    const int gZ = (zTotal + 255) / 256;             // 782
    const int gW = 640;                              // 163840 / 256
    const int padTotal = (mpad - n) * 256 * 2 / 16;  // bufA pad rows in int4 units, 1536
    const int gPad = (padTotal + 255) / 256;         // 6
    const int gEdge = (E + 255) / 256;               // 3125
    const int gGemm = (mpad / 128) * 2;              // 782

    // dispatch 1: zero counters + W transpose + zero bufA pad rows
    k_pre0<<<gZ + gW + gPad, 256, 0, stream>>>(cnt, zTotal, W1, W2, W3, Wt, gZ, gW,
                                               (int*)(bufA + (size_t)n * 256), padTotal);

    // dispatch 2: edge build (atomic service wall) with GEMM1 hidden under it
    k_fused<<<gEdge + gGemm, 256, 0, stream>>>(srcp, dstp, E, cnt, col, x, W1t,
                                               bufB, n, gEdge);

    const int gAgg = (n + 3) / 4;
    // agg1: per-chunk dinv prefetch (NSCALE), applies dinv[src] and dinv[i]
    k_agg<256, 128, true, false, true><<<dim3(gAgg, 2), 256, 0, stream>>>(
        bufB, cnt, col, b1, bufA, nullptr, n, n);

    dim3 gg2(mpad / 128, 2);
    k_gemm<true><<<gg2, 256, 0, stream>>>(bufA, W2t, bufB, cnt, n, 256);
    k_agg<256, 128, true, false, false><<<dim3(gAgg, 2), 256, 0, stream>>>(
        bufB, cnt, col, b2, bufA, nullptr, n, n);

    dim3 gg3(mpad / 128, 1);
    k_gemm<true><<<gg3, 256, 0, stream>>>(bufA, W3t, bufB, cnt, n, 128);
    k_agg<128, 128, false, true, false><<<dim3(gAgg, 1), 256, 0, stream>>>(
        bufB, cnt, col, b3, nullptr, (float*)d_out, n, n);
}

// Round 7
// 337.994 us; speedup vs baseline: 1.3527x; 1.3527x over previous
//
#include <hip/hip_runtime.h>
#include <stdint.h>

// ---------- helpers ----------
typedef short v8s __attribute__((ext_vector_type(8)));
typedef float v4f __attribute__((ext_vector_type(4)));
typedef float v2f __attribute__((ext_vector_type(2)));

#define MAXDEG 64    // Poisson(16) tail: P(deg>64) ~ 5e-19/node -> safe for fixed graph
#define CSTRIDE 16   // one counter per 64B line (measured -6us on the atomic wall, r3)

__device__ inline unsigned short f2bf(float f) {
    union { float f; unsigned u; } c; c.f = f;
    unsigned u = c.u;
    unsigned r = (u + 0x7FFFu + ((u >> 16) & 1u)) >> 16;  // RNE
    return (unsigned short)r;
}
__device__ inline void gl_lds16(const unsigned short* g, unsigned short* l) {
    __builtin_amdgcn_global_load_lds(
        (const __attribute__((address_space(1))) unsigned int*)(g),
        (__attribute__((address_space(3))) unsigned int*)(l), 16, 0, 0);
}

// ---------- fused preprocessing (single pass) ----------
// blocks [0,gE): edge bucket-scatter: p = atomicAdd(cnt[dst]); col[dst*64+p] = src
//   (device-atomic service-rate wall ~54us; x-conv and W-transpose hide under it)
// blocks [gE,gE+gX): x fp32 -> bf16 padded
// blocks [gE+gX,...): W1/W2/W3 -> transposed bf16
__global__ void k_pre1(const int* __restrict__ src, const int* __restrict__ dst, int E,
                       int* __restrict__ cnt, int* __restrict__ col,
                       const float* __restrict__ x, unsigned short* __restrict__ A,
                       int n, int mpad,
                       const float* __restrict__ W1, const float* __restrict__ W2,
                       const float* __restrict__ W3, unsigned short* __restrict__ Wt,
                       int gE, int gX) {
    int b = blockIdx.x;
    if (b < gE) {
        int e = b * 256 + threadIdx.x;
        if (e < E) {
            int d = dst[e];
            int p = atomicAdd(&cnt[(size_t)d * CSTRIDE], 1);
            if (p < MAXDEG) col[(size_t)d * MAXDEG + p] = src[e];
        }
    } else if (b < gE + gX) {
        int g = (b - gE) * 256 + threadIdx.x;  // one float4 group
        int total = mpad * 64;
        if (g >= total) return;
        int row = g >> 6;
        float4 v;
        if (row < n) v = ((const float4*)x)[(size_t)g];
        else v = make_float4(0.f, 0.f, 0.f, 0.f);
        ushort4 o;
        o.x = f2bf(v.x); o.y = f2bf(v.y); o.z = f2bf(v.z); o.w = f2bf(v.w);
        ((ushort4*)A)[(size_t)g] = o;
    } else {
        int idx = (b - gE - gX) * 256 + threadIdx.x;  // < 163840 exact
        const float* W; int base, N;
        if (idx < 65536)       { W = W1; base = 0;      N = 256; }
        else if (idx < 131072) { W = W2; base = 65536;  N = 256; }
        else                   { W = W3; base = 131072; N = 128; }
        int loc = idx - base;
        int nn = loc >> 8;   // K = 256
        int k = loc & 255;
        Wt[idx] = f2bf(W[(size_t)k * N + nn]);
    }
}

// ---------- GEMM: Hs[m,n] = rsqrt(cnt[m]+1) * sum_k A[m,k] * W[k,n] ----------
// launch_bounds(256,4): 4 waves/EU -> 4 blocks/CU (VGPR cap 128; acc 64 + frags 32 fits)
__launch_bounds__(256, 4)
__global__ void k_gemm(const unsigned short* __restrict__ A,
                       const unsigned short* __restrict__ Wt,
                       unsigned short* __restrict__ Hs,
                       const int* __restrict__ cnt, int n, int N) {
    __shared__ unsigned short sA[128 * 32];
    __shared__ unsigned short sB[128 * 32];
    const int t = threadIdx.x;
    const int lane = t & 63;
    const int wave = t >> 6;
    const int wm = wave >> 1, wn = wave & 1;
    const int m0 = blockIdx.x * 128;
    const int n0 = blockIdx.y * 128;

    v4f acc[4][4];
#pragma unroll
    for (int i = 0; i < 4; i++)
#pragma unroll
        for (int j = 0; j < 4; j++)
#pragma unroll
            for (int r = 0; r < 4; r++) acc[i][j][r] = 0.f;

    const int c0 = t, c1 = t + 256;
    const int r0 = c0 >> 2, kc0 = (c0 & 3) * 8;
    const int r1 = c1 >> 2, kc1 = (c1 & 3) * 8;
    const size_t aBase0 = (size_t)(m0 + r0) * 256 + kc0;
    const size_t aBase1 = (size_t)(m0 + r1) * 256 + kc1;
    const size_t bBase0 = (size_t)(n0 + r0) * 256 + kc0;
    const size_t bBase1 = (size_t)(n0 + r1) * 256 + kc1;

    const int q = lane >> 4;
    const int lm = lane & 15;

    for (int k0 = 0; k0 < 256; k0 += 32) {
        __syncthreads();
        gl_lds16(A + aBase0 + k0, &sA[c0 * 8]);
        gl_lds16(A + aBase1 + k0, &sA[c1 * 8]);
        gl_lds16(Wt + bBase0 + k0, &sB[c0 * 8]);
        gl_lds16(Wt + bBase1 + k0, &sB[c1 * 8]);
        __syncthreads();

        v8s afr[4], bfr[4];
#pragma unroll
        for (int i = 0; i < 4; i++) {
            int r = wm * 64 + i * 16 + lm;
            afr[i] = *(const v8s*)&sA[r * 32 + q * 8];
        }
#pragma unroll
        for (int j = 0; j < 4; j++) {
            int nn = wn * 64 + j * 16 + lm;
            bfr[j] = *(const v8s*)&sB[nn * 32 + q * 8];
        }
#pragma unroll
        for (int i = 0; i < 4; i++)
#pragma unroll
            for (int j = 0; j < 4; j++)
                acc[i][j] = __builtin_amdgcn_mfma_f32_16x16x32_bf16(afr[i], bfr[j],
                                                                    acc[i][j], 0, 0, 0);
    }

    // epilogue: C/D layout col=lane&15, row=(lane>>4)*4+reg
#pragma unroll
    for (int i = 0; i < 4; i++) {
        int mbase = m0 + wm * 64 + i * 16 + q * 4;
#pragma unroll
        for (int r = 0; r < 4; r++) {
            int m = mbase + r;
            float s = (m < n) ? rsqrtf((float)(cnt[(size_t)m * CSTRIDE] + 1)) : 0.f;
#pragma unroll
            for (int j = 0; j < 4; j++) {
                int colI = n0 + wn * 64 + j * 16 + lm;
                Hs[(size_t)m * N + colI] = f2bf(acc[i][j][r] * s);
            }
        }
    }
}

// ---------- aggregation: out[i] = act(dinv[i]*(sum_{nbr} hs[src] + hs[i]) + b) ----------
// Hs rows are PRE-SCALED by dinv[src] (gemm epilogue); epilogue here applies dinv[i].
// Channel-split (CS<D) halves the per-phase gather working set for better L2 hits
// (measured win for D=256; CS=64 for D=128 measured regression -> keep unsplit).
// 4-deep gather ILP + 1-deep tail (round-2 proven form; 2-deep middle tier was a
// round-3 regression; per-row/per-chunk scale gathers were round-5/6 disasters on this
// request-slot-limited kernel). Packed-f32 accumulate.
template <int D, int CS, bool RELU, bool F32OUT>
__launch_bounds__(256, 8)
__global__ void k_agg(const unsigned short* __restrict__ Hs,
                      const int* __restrict__ cnt, const int* __restrict__ col,
                      const float* __restrict__ bias,
                      unsigned short* __restrict__ outb, float* __restrict__ outf,
                      int n, int nzero) {
    constexpr int LPN = CS / 8;    // lanes per neighbor row (16 for CS=128)
    constexpr int NPG = 64 / LPN;  // neighbors per gather instruction (4)
    const int lane = threadIdx.x & 63;
    const int i = blockIdx.x * 4 + (threadIdx.x >> 6);
    const int ch0 = blockIdx.y * CS;   // channel slice base
    if (i >= n) return;
    const int g = lane / LPN;      // neighbor slot within the gather
    const int cl = lane % LPN;     // channel chunk (8 channels each)

    v2f acc[4];
#pragma unroll
    for (int k = 0; k < 4; k++) acc[k] = (v2f){0.f, 0.f};

    // unpack bf16 pair as bit-ops -> packed f32 add (lo = u<<16, hi = u&0xffff0000)
    auto accq = [&](unsigned u, int k) {
        union { unsigned uu; float f; } lo, hi;
        lo.uu = u << 16;
        hi.uu = u & 0xffff0000u;
        v2f t; t[0] = lo.f; t[1] = hi.f;
        acc[k] += t;
    };
    auto acc16 = [&](uint4 q) { accq(q.x, 0); accq(q.y, 1); accq(q.z, 2); accq(q.w, 3); };

    const unsigned short* base = Hs + ch0 + cl * 8;
    const int deg = cnt[(size_t)i * CSTRIDE];
    const size_t cbase = (size_t)i * MAXDEG;
    const int T = deg + 1;                       // self + neighbors
    const int Tpad = (T + NPG - 1) & ~(NPG - 1); // pad with zero-row nzero

    for (int b = 0; b < Tpad; b += 64) {
        int t = b + lane;
        int v;
        if (t == 0) v = i;                        // self loop
        else if (t <= deg) v = col[cbase + t - 1];  // padded bucket load
        else v = nzero;                           // zero row pad
        int lim = min(64, Tpad - b);
        int t2 = 0;
        for (; t2 + 4 * NPG <= lim; t2 += 4 * NPG) {
            int c0 = __shfl(v, t2 + 0 * NPG + g);
            int c1 = __shfl(v, t2 + 1 * NPG + g);
            int c2 = __shfl(v, t2 + 2 * NPG + g);
            int c3 = __shfl(v, t2 + 3 * NPG + g);
            uint4 q0 = *(const uint4*)(base + (size_t)c0 * D);
            uint4 q1 = *(const uint4*)(base + (size_t)c1 * D);
            uint4 q2 = *(const uint4*)(base + (size_t)c2 * D);
            uint4 q3 = *(const uint4*)(base + (size_t)c3 * D);
            acc16(q0); acc16(q1); acc16(q2); acc16(q3);
        }
        for (; t2 + NPG <= lim; t2 += NPG) {
            int c0 = __shfl(v, t2 + g);
            uint4 q0 = *(const uint4*)(base + (size_t)c0 * D);
            acc16(q0);
        }
    }

    // reduce across neighbor slots
#pragma unroll
    for (int off = LPN; off < 64; off <<= 1) {
#pragma unroll
        for (int k = 0; k < 4; k++) {
            acc[k][0] += __shfl_xor(acc[k][0], off);
            acc[k][1] += __shfl_xor(acc[k][1], off);
        }
    }

    if (g == 0) {  // lanes 0..LPN-1 write
        float di = rsqrtf((float)(deg + 1));
        float o[8];
#pragma unroll
        for (int k = 0; k < 4; k++) {
            o[2 * k + 0] = di * acc[k][0] + bias[ch0 + cl * 8 + 2 * k + 0];
            o[2 * k + 1] = di * acc[k][1] + bias[ch0 + cl * 8 + 2 * k + 1];
        }
        if (RELU) {
#pragma unroll
            for (int k = 0; k < 8; k++) o[k] = fmaxf(o[k], 0.f);
        }
        if constexpr (F32OUT) {
            float* p = outf + (size_t)i * D + ch0 + cl * 8;
            *(float4*)p = make_float4(o[0], o[1], o[2], o[3]);
            *(float4*)(p + 4) = make_float4(o[4], o[5], o[6], o[7]);
        } else {
            uint4 q;
            q.x = ((unsigned)f2bf(o[1]) << 16) | f2bf(o[0]);
            q.y = ((unsigned)f2bf(o[3]) << 16) | f2bf(o[2]);
            q.z = ((unsigned)f2bf(o[5]) << 16) | f2bf(o[4]);
            q.w = ((unsigned)f2bf(o[7]) << 16) | f2bf(o[6]);
            *(uint4*)(outb + (size_t)i * D + ch0 + cl * 8) = q;
        }
    }
}

// ---------- launch ----------
extern "C" void kernel_launch(void* const* d_in, const int* in_sizes, int n_in,
                              void* d_out, int out_size, void* d_ws, size_t ws_size,
                              hipStream_t stream) {
    const float* x  = (const float*)d_in[0];
    const int*   ei = (const int*)d_in[1];   // [2, E] int32
    const float* W1 = (const float*)d_in[2];
    const float* b1 = (const float*)d_in[3];
    const float* W2 = (const float*)d_in[4];
    const float* b2 = (const float*)d_in[5];
    const float* W3 = (const float*)d_in[6];
    const float* b3 = (const float*)d_in[7];

    const int n = in_sizes[0] / 256;     // 50000
    const int E = in_sizes[1] / 2;       // 800000
    const int mpad = ((n + 127) / 128) * 128;  // 50048

    char* ws = (char*)d_ws;
    size_t off = 0;
    auto alloc = [&](size_t bytes) -> void* {
        void* p = ws + off;
        off += (bytes + 255) & ~(size_t)255;
        return p;
    };
    int* cnt      = (int*)alloc((size_t)mpad * CSTRIDE * 4);  // padded counters, 3.2MB
    int* col      = (int*)alloc((size_t)n * MAXDEG * 4);      // padded buckets, 12.8MB
    unsigned short* Wt = (unsigned short*)alloc((size_t)163840 * 2);
    unsigned short* W1t = Wt;
    unsigned short* W2t = Wt + 65536;
    unsigned short* W3t = Wt + 131072;
    unsigned short* bufA = (unsigned short*)alloc((size_t)mpad * 256 * 2);
    unsigned short* bufB = (unsigned short*)alloc((size_t)mpad * 256 * 2);
    (void)ws_size; (void)n_in; (void)out_size;

    const int* srcp = ei;
    const int* dstp = ei + E;
    const int gE = (E + 255) / 256;            // 3125
    const int gX = (mpad * 64 + 255) / 256;    // 12512
    const int gW = 640;                        // 163840 / 256

    hipMemsetAsync(cnt, 0, (size_t)n * CSTRIDE * 4, stream);

    k_pre1<<<gE + gX + gW, 256, 0, stream>>>(srcp, dstp, E, cnt, col, x, bufA, n, mpad,
                                             W1, W2, W3, Wt, gE, gX);

    const int gAgg = (n + 3) / 4;
    dim3 gg1(mpad / 128, 2);
    k_gemm<<<gg1, 256, 0, stream>>>(bufA, W1t, bufB, cnt, n, 256);
    k_agg<256, 128, true, false><<<dim3(gAgg, 2), 256, 0, stream>>>(
        bufB, cnt, col, b1, bufA, nullptr, n, n);
    k_gemm<<<gg1, 256, 0, stream>>>(bufA, W2t, bufB, cnt, n, 256);
    k_agg<256, 128, true, false><<<dim3(gAgg, 2), 256, 0, stream>>>(
        bufB, cnt, col, b2, bufA, nullptr, n, n);
    dim3 gg3(mpad / 128, 1);
    k_gemm<<<gg3, 256, 0, stream>>>(bufA, W3t, bufB, cnt, n, 128);
    k_agg<128, 128, false, true><<<dim3(gAgg, 1), 256, 0, stream>>>(
        bufB, cnt, col, b3, nullptr, (float*)d_out, n, n);
}

// Round 8
// 334.506 us; speedup vs baseline: 1.3668x; 1.0104x over previous
//
#include <hip/hip_runtime.h>
#include <stdint.h>

// ---------- helpers ----------
typedef short v8s __attribute__((ext_vector_type(8)));
typedef float v4f __attribute__((ext_vector_type(4)));
typedef float v2f __attribute__((ext_vector_type(2)));

#define MAXDEG 64    // Poisson(16) tail: P(deg>64) ~ 5e-19/node -> safe for fixed graph
#define CSTRIDE 16   // one counter per 64B line (measured -6us on the atomic wall, r3)

__device__ inline unsigned short f2bf(float f) {
    union { float f; unsigned u; } c; c.f = f;
    unsigned u = c.u;
    unsigned r = (u + 0x7FFFu + ((u >> 16) & 1u)) >> 16;  // RNE
    return (unsigned short)r;
}
__device__ inline void gl_lds16(const unsigned short* g, unsigned short* l) {
    __builtin_amdgcn_global_load_lds(
        (const __attribute__((address_space(1))) unsigned int*)(g),
        (__attribute__((address_space(3))) unsigned int*)(l), 16, 0, 0);
}

// ---------- fused preprocessing (single pass) ---------- (unchanged, proven r7)
__global__ void k_pre1(const int* __restrict__ src, const int* __restrict__ dst, int E,
                       int* __restrict__ cnt, int* __restrict__ col,
                       const float* __restrict__ x, unsigned short* __restrict__ A,
                       int n, int mpad,
                       const float* __restrict__ W1, const float* __restrict__ W2,
                       const float* __restrict__ W3, unsigned short* __restrict__ Wt,
                       int gE, int gX) {
    int b = blockIdx.x;
    if (b < gE) {
        int e = b * 256 + threadIdx.x;
        if (e < E) {
            int d = dst[e];
            int p = atomicAdd(&cnt[(size_t)d * CSTRIDE], 1);
            if (p < MAXDEG) col[(size_t)d * MAXDEG + p] = src[e];
        }
    } else if (b < gE + gX) {
        int g = (b - gE) * 256 + threadIdx.x;  // one float4 group
        int total = mpad * 64;
        if (g >= total) return;
        int row = g >> 6;
        float4 v;
        if (row < n) v = ((const float4*)x)[(size_t)g];
        else v = make_float4(0.f, 0.f, 0.f, 0.f);
        ushort4 o;
        o.x = f2bf(v.x); o.y = f2bf(v.y); o.z = f2bf(v.z); o.w = f2bf(v.w);
        ((ushort4*)A)[(size_t)g] = o;
    } else {
        int idx = (b - gE - gX) * 256 + threadIdx.x;  // < 163840 exact
        const float* W; int base, N;
        if (idx < 65536)       { W = W1; base = 0;      N = 256; }
        else if (idx < 131072) { W = W2; base = 65536;  N = 256; }
        else                   { W = W3; base = 131072; N = 128; }
        int loc = idx - base;
        int nn = loc >> 8;   // K = 256
        int k = loc & 255;
        Wt[idx] = f2bf(W[(size_t)k * N + nn]);
    }
}

// ---------- GEMM: Hs[m,n] = rsqrt(cnt[m]+1) * sum_k A[m,k] * W[k,n] ----------
// r8 rework (agg/pre untouched):
//  - BK=64 (4 k-iters, half the barriers)
//  - XOR-swizzled LDS layout: slot s of row r holds k-chunk s^(r&7); achieved by
//    pre-swizzling the GLOBAL source addr (gl_lds16 dest must stay linear, m104/m173).
//    Fragment reads use chunk (chi^(lm&7)) -> 8-chunk bank spread -> 2-way (free)
//    instead of the old 8-way conflict on every ds_read_b128.
//  - LDS-bounce epilogue: acc -> LDS (8KB per i-chunk) -> coalesced uint4 stores
//    (8 per thread vs 64 scalar 2B stores). MFMA/k order unchanged -> bitwise-same.
__launch_bounds__(256, 4)
__global__ void k_gemm(const unsigned short* __restrict__ A,
                       const unsigned short* __restrict__ Wt,
                       unsigned short* __restrict__ Hs,
                       const int* __restrict__ cnt, int n, int N) {
    __shared__ unsigned short sA[128 * 64];   // 16 KB
    __shared__ unsigned short sB[128 * 64];   // 16 KB
    const int t = threadIdx.x;
    const int lane = t & 63;
    const int wave = t >> 6;
    const int wm = wave >> 1, wn = wave & 1;
    const int m0 = blockIdx.x * 128;
    const int n0 = blockIdx.y * 128;

    v4f acc[4][4];
#pragma unroll
    for (int i = 0; i < 4; i++)
#pragma unroll
        for (int j = 0; j < 4; j++)
#pragma unroll
            for (int r = 0; r < 4; r++) acc[i][j][r] = 0.f;

    const int q = lane >> 4;
    const int lm = lane & 15;
    const int l7 = lm & 7;

    // staging positions: c in [0,1024): row r=c>>3, slot s=c&7 holds chunk s^(r&7)
    int sRow[4], sOff[4];
#pragma unroll
    for (int u = 0; u < 4; u++) {
        int c = t + u * 256;
        int r = c >> 3;
        int ch = (c & 7) ^ (r & 7);
        sRow[u] = r;
        sOff[u] = ch * 8;
    }

    for (int k0 = 0; k0 < 256; k0 += 64) {
        __syncthreads();
#pragma unroll
        for (int u = 0; u < 4; u++) {
            int c = t + u * 256;
            gl_lds16(A + (size_t)(m0 + sRow[u]) * 256 + k0 + sOff[u], &sA[c * 8]);
            gl_lds16(Wt + (size_t)(n0 + sRow[u]) * 256 + k0 + sOff[u], &sB[c * 8]);
        }
        __syncthreads();

#pragma unroll
        for (int kk = 0; kk < 2; kk++) {        // chunk base: q or q+4
            const int chi = q + kk * 4;
            v8s afr[4], bfr[4];
#pragma unroll
            for (int i = 0; i < 4; i++) {
                int r = wm * 64 + i * 16 + lm;
                afr[i] = *(const v8s*)&sA[r * 64 + ((chi ^ l7) * 8)];
            }
#pragma unroll
            for (int j = 0; j < 4; j++) {
                int nn = wn * 64 + j * 16 + lm;
                bfr[j] = *(const v8s*)&sB[nn * 64 + ((chi ^ l7) * 8)];
            }
#pragma unroll
            for (int i = 0; i < 4; i++)
#pragma unroll
                for (int j = 0; j < 4; j++)
                    acc[i][j] = __builtin_amdgcn_mfma_f32_16x16x32_bf16(
                        afr[i], bfr[j], acc[i][j], 0, 0, 0);
        }
    }

    // ---- LDS-bounce epilogue: C/D layout col=lane&15, row=(lane>>4)*4+reg ----
    unsigned short* sC = sA;                    // reuse 8 KB of sA
    const int rRow = t >> 3;                    // read-phase row in [0,32)
    const int rCh  = t & 7;                     // read-phase chunk
#pragma unroll
    for (int i = 0; i < 4; i++) {
        __syncthreads();                        // sC free (prev read / k-loop done)
#pragma unroll
        for (int r = 0; r < 4; r++) {
            int m = m0 + wm * 64 + i * 16 + q * 4 + r;
            float s = (m < n) ? rsqrtf((float)(cnt[(size_t)m * CSTRIDE] + 1)) : 0.f;
            int rho = wm * 16 + q * 4 + r;
#pragma unroll
            for (int j = 0; j < 4; j++) {
                int colI = wn * 64 + j * 16 + lm;
                sC[rho * 128 + colI] = f2bf(acc[i][j][r] * s);
            }
        }
        __syncthreads();
        int m = m0 + (rRow >> 4) * 64 + i * 16 + (rRow & 15);
#pragma unroll
        for (int h = 0; h < 2; h++) {
            int ch = rCh + h * 8;
            uint4 v = *(const uint4*)&sC[rRow * 128 + ch * 8];
            *(uint4*)&Hs[(size_t)m * N + n0 + ch * 8] = v;
        }
    }
}

// ---------- aggregation ---------- (unchanged, proven r7)
template <int D, int CS, bool RELU, bool F32OUT>
__launch_bounds__(256, 8)
__global__ void k_agg(const unsigned short* __restrict__ Hs,
                      const int* __restrict__ cnt, const int* __restrict__ col,
                      const float* __restrict__ bias,
                      unsigned short* __restrict__ outb, float* __restrict__ outf,
                      int n, int nzero) {
    constexpr int LPN = CS / 8;    // lanes per neighbor row (16 for CS=128)
    constexpr int NPG = 64 / LPN;  // neighbors per gather instruction (4)
    const int lane = threadIdx.x & 63;
    const int i = blockIdx.x * 4 + (threadIdx.x >> 6);
    const int ch0 = blockIdx.y * CS;   // channel slice base
    if (i >= n) return;
    const int g = lane / LPN;      // neighbor slot within the gather
    const int cl = lane % LPN;     // channel chunk (8 channels each)

    v2f acc[4];
#pragma unroll
    for (int k = 0; k < 4; k++) acc[k] = (v2f){0.f, 0.f};

    auto accq = [&](unsigned u, int k) {
        union { unsigned uu; float f; } lo, hi;
        lo.uu = u << 16;
        hi.uu = u & 0xffff0000u;
        v2f t; t[0] = lo.f; t[1] = hi.f;
        acc[k] += t;
    };
    auto acc16 = [&](uint4 q) { accq(q.x, 0); accq(q.y, 1); accq(q.z, 2); accq(q.w, 3); };

    const unsigned short* base = Hs + ch0 + cl * 8;
    const int deg = cnt[(size_t)i * CSTRIDE];
    const size_t cbase = (size_t)i * MAXDEG;
    const int T = deg + 1;                       // self + neighbors
    const int Tpad = (T + NPG - 1) & ~(NPG - 1); // pad with zero-row nzero

    for (int b = 0; b < Tpad; b += 64) {
        int t = b + lane;
        int v;
        if (t == 0) v = i;                        // self loop
        else if (t <= deg) v = col[cbase + t - 1];  // padded bucket load
        else v = nzero;                           // zero row pad
        int lim = min(64, Tpad - b);
        int t2 = 0;
        for (; t2 + 4 * NPG <= lim; t2 += 4 * NPG) {
            int c0 = __shfl(v, t2 + 0 * NPG + g);
            int c1 = __shfl(v, t2 + 1 * NPG + g);
            int c2 = __shfl(v, t2 + 2 * NPG + g);
            int c3 = __shfl(v, t2 + 3 * NPG + g);
            uint4 q0 = *(const uint4*)(base + (size_t)c0 * D);
            uint4 q1 = *(const uint4*)(base + (size_t)c1 * D);
            uint4 q2 = *(const uint4*)(base + (size_t)c2 * D);
            uint4 q3 = *(const uint4*)(base + (size_t)c3 * D);
            acc16(q0); acc16(q1); acc16(q2); acc16(q3);
        }
        for (; t2 + NPG <= lim; t2 += NPG) {
            int c0 = __shfl(v, t2 + g);
            uint4 q0 = *(const uint4*)(base + (size_t)c0 * D);
            acc16(q0);
        }
    }

#pragma unroll
    for (int off = LPN; off < 64; off <<= 1) {
#pragma unroll
        for (int k = 0; k < 4; k++) {
            acc[k][0] += __shfl_xor(acc[k][0], off);
            acc[k][1] += __shfl_xor(acc[k][1], off);
        }
    }

    if (g == 0) {  // lanes 0..LPN-1 write
        float di = rsqrtf((float)(deg + 1));
        float o[8];
#pragma unroll
        for (int k = 0; k < 4; k++) {
            o[2 * k + 0] = di * acc[k][0] + bias[ch0 + cl * 8 + 2 * k + 0];
            o[2 * k + 1] = di * acc[k][1] + bias[ch0 + cl * 8 + 2 * k + 1];
        }
        if (RELU) {
#pragma unroll
            for (int k = 0; k < 8; k++) o[k] = fmaxf(o[k], 0.f);
        }
        if constexpr (F32OUT) {
            float* p = outf + (size_t)i * D + ch0 + cl * 8;
            *(float4*)p = make_float4(o[0], o[1], o[2], o[3]);
            *(float4*)(p + 4) = make_float4(o[4], o[5], o[6], o[7]);
        } else {
            uint4 q;
            q.x = ((unsigned)f2bf(o[1]) << 16) | f2bf(o[0]);
            q.y = ((unsigned)f2bf(o[3]) << 16) | f2bf(o[2]);
            q.z = ((unsigned)f2bf(o[5]) << 16) | f2bf(o[4]);
            q.w = ((unsigned)f2bf(o[7]) << 16) | f2bf(o[6]);
            *(uint4*)(outb + (size_t)i * D + ch0 + cl * 8) = q;
        }
    }
}

// ---------- launch ----------
extern "C" void kernel_launch(void* const* d_in, const int* in_sizes, int n_in,
                              void* d_out, int out_size, void* d_ws, size_t ws_size,
                              hipStream_t stream) {
    const float* x  = (const float*)d_in[0];
    const int*   ei = (const int*)d_in[1];   // [2, E] int32
    const float* W1 = (const float*)d_in[2];
    const float* b1 = (const float*)d_in[3];
    const float* W2 = (const float*)d_in[4];
    const float* b2 = (const float*)d_in[5];
    const float* W3 = (const float*)d_in[6];
    const float* b3 = (const float*)d_in[7];

    const int n = in_sizes[0] / 256;     // 50000
    const int E = in_sizes[1] / 2;       // 800000
    const int mpad = ((n + 127) / 128) * 128;  // 50048

    char* ws = (char*)d_ws;
    size_t off = 0;
    auto alloc = [&](size_t bytes) -> void* {
        void* p = ws + off;
        off += (bytes + 255) & ~(size_t)255;
        return p;
    };
    int* cnt      = (int*)alloc((size_t)mpad * CSTRIDE * 4);  // padded counters, 3.2MB
    int* col      = (int*)alloc((size_t)n * MAXDEG * 4);      // padded buckets, 12.8MB
    unsigned short* Wt = (unsigned short*)alloc((size_t)163840 * 2);
    unsigned short* W1t = Wt;
    unsigned short* W2t = Wt + 65536;
    unsigned short* W3t = Wt + 131072;
    unsigned short* bufA = (unsigned short*)alloc((size_t)mpad * 256 * 2);
    unsigned short* bufB = (unsigned short*)alloc((size_t)mpad * 256 * 2);
    (void)ws_size; (void)n_in; (void)out_size;

    const int* srcp = ei;
    const int* dstp = ei + E;
    const int gE = (E + 255) / 256;            // 3125
    const int gX = (mpad * 64 + 255) / 256;    // 12512
    const int gW = 640;                        // 163840 / 256

    hipMemsetAsync(cnt, 0, (size_t)n * CSTRIDE * 4, stream);

    k_pre1<<<gE + gX + gW, 256, 0, stream>>>(srcp, dstp, E, cnt, col, x, bufA, n, mpad,
                                             W1, W2, W3, Wt, gE, gX);

    const int gAgg = (n + 3) / 4;
    dim3 gg1(mpad / 128, 2);
    k_gemm<<<gg1, 256, 0, stream>>>(bufA, W1t, bufB, cnt, n, 256);
    k_agg<256, 128, true, false><<<dim3(gAgg, 2), 256, 0, stream>>>(
        bufB, cnt, col, b1, bufA, nullptr, n, n);
    k_gemm<<<gg1, 256, 0, stream>>>(bufA, W2t, bufB, cnt, n, 256);
    k_agg<256, 128, true, false><<<dim3(gAgg, 2), 256, 0, stream>>>(
        bufB, cnt, col, b2, bufA, nullptr, n, n);
    dim3 gg3(mpad / 128, 1);
    k_gemm<<<gg3, 256, 0, stream>>>(bufA, W3t, bufB, cnt, n, 128);
    k_agg<128, 128, false, true><<<dim3(gAgg, 1), 256, 0, stream>>>(
        bufB, cnt, col, b3, nullptr, (float*)d_out, n, n);
}

// Round 9
// 328.320 us; speedup vs baseline: 1.3926x; 1.0188x over previous
//
#include <hip/hip_runtime.h>
#include <stdint.h>

// ---------- helpers ----------
typedef short v8s __attribute__((ext_vector_type(8)));
typedef float v4f __attribute__((ext_vector_type(4)));
typedef float v2f __attribute__((ext_vector_type(2)));

#define MAXDEG 64    // Poisson(16) tail: P(deg>64) ~ 5e-19/node -> safe for fixed graph
#define CSTRIDE 16   // one counter per 64B line
#define CAP 5120     // bucket capacity: mean 4082, sigma 64 -> 16 sigma headroom
#define EPB 4096     // edges per binA block (2 macro-rounds of 8/thread)

__device__ inline unsigned short f2bf(float f) {
    union { float f; unsigned u; } c; c.f = f;
    unsigned u = c.u;
    unsigned r = (u + 0x7FFFu + ((u >> 16) & 1u)) >> 16;  // RNE
    return (unsigned short)r;
}
__device__ inline void gl_lds16(const unsigned short* g, unsigned short* l) {
    __builtin_amdgcn_global_load_lds(
        (const __attribute__((address_space(1))) unsigned int*)(g),
        (__attribute__((address_space(3))) unsigned int*)(l), 16, 0, 0);
}
__device__ inline v8s cvt8(float4 a, float4 b) {  // 8 f32 -> 8 bf16 (same bits as f2bf)
    v8s r;
    r[0] = (short)f2bf(a.x); r[1] = (short)f2bf(a.y);
    r[2] = (short)f2bf(a.z); r[3] = (short)f2bf(a.w);
    r[4] = (short)f2bf(b.x); r[5] = (short)f2bf(b.y);
    r[6] = (short)f2bf(b.z); r[7] = (short)f2bf(b.w);
    return r;
}

// ---------- binA: coarse bucket sort (kills the 800k-global-atomic wall) ----------
// blocks [0,gEdge): LDS-histogram dst>>8 -> 1 global atomicAdd per bucket per round
//   (38k total vs 800k) -> write {src, dst&255} runs into bucket storage.
// blocks [gEdge,gEdge+gW): W1/W2/W3 -> transposed bf16.
// blocks [gEdge+gW,..): zero bufA pad rows [n,mpad) (incl. the nzero row).
__launch_bounds__(256, 4)
__global__ void k_binA(const int* __restrict__ src, const int* __restrict__ dst, int E,
                       int* __restrict__ gcnt, int2* __restrict__ bstore,
                       const float* __restrict__ W1, const float* __restrict__ W2,
                       const float* __restrict__ W3, unsigned short* __restrict__ Wt,
                       int* __restrict__ apad, int padTotal, int gEdge, int gW) {
    int b = blockIdx.x;
    int t = threadIdx.x;
    if (b < gEdge) {
        __shared__ int cntL[256];
        __shared__ int baseL[256];
        for (int rr = 0; rr < 2; rr++) {
            cntL[t] = 0;
            __syncthreads();
            int eb = b * EPB + rr * 2048;
            int bb[8], sv[8], dl[8], pp[8];
#pragma unroll
            for (int k = 0; k < 8; k++) {
                int e = eb + k * 256 + t;
                if (e < E) {
                    int d = dst[e];
                    bb[k] = d >> 8; dl[k] = d & 255; sv[k] = src[e];
                    pp[k] = atomicAdd(&cntL[bb[k]], 1);
                } else bb[k] = -1;
            }
            __syncthreads();
            int myc = cntL[t];
            baseL[t] = myc ? atomicAdd(&gcnt[t * CSTRIDE], myc) : 0;
            __syncthreads();
#pragma unroll
            for (int k = 0; k < 8; k++)
                if (bb[k] >= 0) {
                    int pos = baseL[bb[k]] + pp[k];
                    if (pos < CAP)
                        bstore[(size_t)bb[k] * CAP + pos] = make_int2(sv[k], dl[k]);
                }
            __syncthreads();
        }
    } else if (b < gEdge + gW) {
        int idx = (b - gEdge) * 256 + t;  // < 163840 exact
        const float* W; int base, N;
        if (idx < 65536)       { W = W1; base = 0;      N = 256; }
        else if (idx < 131072) { W = W2; base = 65536;  N = 256; }
        else                   { W = W3; base = 131072; N = 128; }
        int loc = idx - base;
        int nn = loc >> 8;   // K = 256
        int k = loc & 255;
        Wt[idx] = f2bf(W[(size_t)k * N + nn]);
    } else {
        int idx = (b - gEdge - gW) * 256 + t;  // int4 granularity
        if (idx < padTotal) ((int4*)apad)[idx] = make_int4(0, 0, 0, 0);
    }
}

// ---------- binB: per-bucket fine build via LDS atomics (on-CU, no coherence wall) ----
__global__ void k_binB(const int* __restrict__ gcnt, const int2* __restrict__ bstore,
                       int* __restrict__ cnt, int* __restrict__ col, int n) {
    __shared__ int cntL[256];
    int b = blockIdx.x, t = threadIdx.x;
    cntL[t] = 0;
    __syncthreads();
    int total = min(gcnt[b * CSTRIDE], CAP);
    for (int i = t; i < total; i += 256) {
        int2 e = bstore[(size_t)b * CAP + i];
        int p = atomicAdd(&cntL[e.y], 1);
        // col region per bucket is 64KB -> L2-local scatter, HBM writes stay 12.8MB
        if (p < MAXDEG) col[((size_t)(b * 256 + e.y)) * MAXDEG + p] = e.x;
    }
    __syncthreads();
    int node = b * 256 + t;
    if (node < n) cnt[(size_t)node * CSTRIDE] = cntL[t];
}

// ---------- GEMM: Hs[m,n] = rsqrt(cnt[m]+1) * sum_k A[m,k] * W[k,n] ----------
// r8 structure (BK=64, XOR-swizzled LDS via pre-swizzled source, LDS-bounce epilogue).
// CONVA (gemm1): A read from f32 x, converted in-register during staging -> the 77MB
// x->bf16 pre-pass is deleted. Same f2bf RNE bits -> bitwise-identical Hs.
template <bool CONVA>
__launch_bounds__(256, 4)
__global__ void k_gemm(const float* __restrict__ Af,
                       const unsigned short* __restrict__ Ab,
                       const unsigned short* __restrict__ Wt,
                       unsigned short* __restrict__ Hs,
                       const int* __restrict__ cnt, int n, int N) {
    __shared__ unsigned short sA[128 * 64];   // 16 KB
    __shared__ unsigned short sB[128 * 64];   // 16 KB
    const int t = threadIdx.x;
    const int lane = t & 63;
    const int wave = t >> 6;
    const int wm = wave >> 1, wn = wave & 1;
    const int m0 = blockIdx.x * 128;
    const int n0 = blockIdx.y * 128;

    v4f acc[4][4];
#pragma unroll
    for (int i = 0; i < 4; i++)
#pragma unroll
        for (int j = 0; j < 4; j++)
#pragma unroll
            for (int r = 0; r < 4; r++) acc[i][j][r] = 0.f;

    const int q = lane >> 4;
    const int lm = lane & 15;
    const int l7 = lm & 7;

    // staging positions: c in [0,1024): row r=c>>3, slot s=c&7 holds chunk s^(r&7)
    int sRow[4], sOff[4];
#pragma unroll
    for (int u = 0; u < 4; u++) {
        int c = t + u * 256;
        int r = c >> 3;
        int ch = (c & 7) ^ (r & 7);
        sRow[u] = r;
        sOff[u] = ch * 8;
    }

    for (int k0 = 0; k0 < 256; k0 += 64) {
        __syncthreads();
#pragma unroll
        for (int u = 0; u < 4; u++) {
            int c = t + u * 256;
            if constexpr (CONVA) {
                float4 u0, u1;
                if (m0 + sRow[u] < n) {
                    const float* p = Af + (size_t)(m0 + sRow[u]) * 256 + k0 + sOff[u];
                    u0 = *(const float4*)p;
                    u1 = *(const float4*)(p + 4);
                } else { u0 = make_float4(0.f, 0.f, 0.f, 0.f); u1 = u0; }
                *(v8s*)&sA[c * 8] = cvt8(u0, u1);
            } else {
                gl_lds16(Ab + (size_t)(m0 + sRow[u]) * 256 + k0 + sOff[u], &sA[c * 8]);
            }
            gl_lds16(Wt + (size_t)(n0 + sRow[u]) * 256 + k0 + sOff[u], &sB[c * 8]);
        }
        __syncthreads();

#pragma unroll
        for (int kk = 0; kk < 2; kk++) {        // chunk base: q or q+4
            const int chi = q + kk * 4;
            v8s afr[4], bfr[4];
#pragma unroll
            for (int i = 0; i < 4; i++) {
                int r = wm * 64 + i * 16 + lm;
                afr[i] = *(const v8s*)&sA[r * 64 + ((chi ^ l7) * 8)];
            }
#pragma unroll
            for (int j = 0; j < 4; j++) {
                int nn = wn * 64 + j * 16 + lm;
                bfr[j] = *(const v8s*)&sB[nn * 64 + ((chi ^ l7) * 8)];
            }
#pragma unroll
            for (int i = 0; i < 4; i++)
#pragma unroll
                for (int j = 0; j < 4; j++)
                    acc[i][j] = __builtin_amdgcn_mfma_f32_16x16x32_bf16(
                        afr[i], bfr[j], acc[i][j], 0, 0, 0);
        }
    }

    // ---- LDS-bounce epilogue: C/D layout col=lane&15, row=(lane>>4)*4+reg ----
    unsigned short* sC = sA;                    // reuse 8 KB of sA
    const int rRow = t >> 3;                    // read-phase row in [0,32)
    const int rCh  = t & 7;                     // read-phase chunk
#pragma unroll
    for (int i = 0; i < 4; i++) {
        __syncthreads();                        // sC free (prev read / k-loop done)
#pragma unroll
        for (int r = 0; r < 4; r++) {
            int m = m0 + wm * 64 + i * 16 + q * 4 + r;
            float s = (m < n) ? rsqrtf((float)(cnt[(size_t)m * CSTRIDE] + 1)) : 0.f;
            int rho = wm * 16 + q * 4 + r;
#pragma unroll
            for (int j = 0; j < 4; j++) {
                int colI = wn * 64 + j * 16 + lm;
                sC[rho * 128 + colI] = f2bf(acc[i][j][r] * s);
            }
        }
        __syncthreads();
        int m = m0 + (rRow >> 4) * 64 + i * 16 + (rRow & 15);
#pragma unroll
        for (int h = 0; h < 2; h++) {
            int ch = rCh + h * 8;
            uint4 v = *(const uint4*)&sC[rRow * 128 + ch * 8];
            *(uint4*)&Hs[(size_t)m * N + n0 + ch * 8] = v;
        }
    }
}

// ---------- aggregation ---------- (unchanged, proven r7/r8)
template <int D, int CS, bool RELU, bool F32OUT>
__launch_bounds__(256, 8)
__global__ void k_agg(const unsigned short* __restrict__ Hs,
                      const int* __restrict__ cnt, const int* __restrict__ col,
                      const float* __restrict__ bias,
                      unsigned short* __restrict__ outb, float* __restrict__ outf,
                      int n, int nzero) {
    constexpr int LPN = CS / 8;    // lanes per neighbor row (16 for CS=128)
    constexpr int NPG = 64 / LPN;  // neighbors per gather instruction (4)
    const int lane = threadIdx.x & 63;
    const int i = blockIdx.x * 4 + (threadIdx.x >> 6);
    const int ch0 = blockIdx.y * CS;   // channel slice base
    if (i >= n) return;
    const int g = lane / LPN;      // neighbor slot within the gather
    const int cl = lane % LPN;     // channel chunk (8 channels each)

    v2f acc[4];
#pragma unroll
    for (int k = 0; k < 4; k++) acc[k] = (v2f){0.f, 0.f};

    auto accq = [&](unsigned u, int k) {
        union { unsigned uu; float f; } lo, hi;
        lo.uu = u << 16;
        hi.uu = u & 0xffff0000u;
        v2f t; t[0] = lo.f; t[1] = hi.f;
        acc[k] += t;
    };
    auto acc16 = [&](uint4 q) { accq(q.x, 0); accq(q.y, 1); accq(q.z, 2); accq(q.w, 3); };

    const unsigned short* base = Hs + ch0 + cl * 8;
    const int deg = cnt[(size_t)i * CSTRIDE];
    const size_t cbase = (size_t)i * MAXDEG;
    const int T = deg + 1;                       // self + neighbors
    const int Tpad = (T + NPG - 1) & ~(NPG - 1); // pad with zero-row nzero

    for (int b = 0; b < Tpad; b += 64) {
        int t = b + lane;
        int v;
        if (t == 0) v = i;                        // self loop
        else if (t <= deg) v = col[cbase + t - 1];  // padded bucket load
        else v = nzero;                           // zero row pad
        int lim = min(64, Tpad - b);
        int t2 = 0;
        for (; t2 + 4 * NPG <= lim; t2 += 4 * NPG) {
            int c0 = __shfl(v, t2 + 0 * NPG + g);
            int c1 = __shfl(v, t2 + 1 * NPG + g);
            int c2 = __shfl(v, t2 + 2 * NPG + g);
            int c3 = __shfl(v, t2 + 3 * NPG + g);
            uint4 q0 = *(const uint4*)(base + (size_t)c0 * D);
            uint4 q1 = *(const uint4*)(base + (size_t)c1 * D);
            uint4 q2 = *(const uint4*)(base + (size_t)c2 * D);
            uint4 q3 = *(const uint4*)(base + (size_t)c3 * D);
            acc16(q0); acc16(q1); acc16(q2); acc16(q3);
        }
        for (; t2 + NPG <= lim; t2 += NPG) {
            int c0 = __shfl(v, t2 + g);
            uint4 q0 = *(const uint4*)(base + (size_t)c0 * D);
            acc16(q0);
        }
    }

#pragma unroll
    for (int off = LPN; off < 64; off <<= 1) {
#pragma unroll
        for (int k = 0; k < 4; k++) {
            acc[k][0] += __shfl_xor(acc[k][0], off);
            acc[k][1] += __shfl_xor(acc[k][1], off);
        }
    }

    if (g == 0) {  // lanes 0..LPN-1 write
        float di = rsqrtf((float)(deg + 1));
        float o[8];
#pragma unroll
        for (int k = 0; k < 4; k++) {
            o[2 * k + 0] = di * acc[k][0] + bias[ch0 + cl * 8 + 2 * k + 0];
            o[2 * k + 1] = di * acc[k][1] + bias[ch0 + cl * 8 + 2 * k + 1];
        }
        if (RELU) {
#pragma unroll
            for (int k = 0; k < 8; k++) o[k] = fmaxf(o[k], 0.f);
        }
        if constexpr (F32OUT) {
            float* p = outf + (size_t)i * D + ch0 + cl * 8;
            *(float4*)p = make_float4(o[0], o[1], o[2], o[3]);
            *(float4*)(p + 4) = make_float4(o[4], o[5], o[6], o[7]);
        } else {
            uint4 q;
            q.x = ((unsigned)f2bf(o[1]) << 16) | f2bf(o[0]);
            q.y = ((unsigned)f2bf(o[3]) << 16) | f2bf(o[2]);
            q.z = ((unsigned)f2bf(o[5]) << 16) | f2bf(o[4]);
            q.w = ((unsigned)f2bf(o[7]) << 16) | f2bf(o[6]);
            *(uint4*)(outb + (size_t)i * D + ch0 + cl * 8) = q;
        }
    }
}

// ---------- launch ----------
extern "C" void kernel_launch(void* const* d_in, const int* in_sizes, int n_in,
                              void* d_out, int out_size, void* d_ws, size_t ws_size,
                              hipStream_t stream) {
    const float* x  = (const float*)d_in[0];
    const int*   ei = (const int*)d_in[1];   // [2, E] int32
    const float* W1 = (const float*)d_in[2];
    const float* b1 = (const float*)d_in[3];
    const float* W2 = (const float*)d_in[4];
    const float* b2 = (const float*)d_in[5];
    const float* W3 = (const float*)d_in[6];
    const float* b3 = (const float*)d_in[7];

    const int n = in_sizes[0] / 256;     // 50000
    const int E = in_sizes[1] / 2;       // 800000
    const int mpad = ((n + 127) / 128) * 128;  // 50048

    char* ws = (char*)d_ws;
    size_t off = 0;
    auto alloc = [&](size_t bytes) -> void* {
        void* p = ws + off;
        off += (bytes + 255) & ~(size_t)255;
        return p;
    };
    int* cnt      = (int*)alloc((size_t)mpad * CSTRIDE * 4);  // padded counters, 3.2MB
    int* col      = (int*)alloc((size_t)n * MAXDEG * 4);      // padded buckets, 12.8MB
    int* gcnt     = (int*)alloc((size_t)256 * CSTRIDE * 4);   // bucket counters, 16KB
    int2* bstore  = (int2*)alloc((size_t)196 * CAP * 8);      // bucket storage, 8MB
    unsigned short* Wt = (unsigned short*)alloc((size_t)163840 * 2);
    unsigned short* W1t = Wt;
    unsigned short* W2t = Wt + 65536;
    unsigned short* W3t = Wt + 131072;
    unsigned short* bufA = (unsigned short*)alloc((size_t)mpad * 256 * 2);
    unsigned short* bufB = (unsigned short*)alloc((size_t)mpad * 256 * 2);
    (void)ws_size; (void)n_in; (void)out_size;

    const int* srcp = ei;
    const int* dstp = ei + E;
    const int nb = (n + 255) / 256;                  // 196 buckets
    const int gEdge = (E + EPB - 1) / EPB;           // 196
    const int gW = 640;                              // 163840 / 256
    const int padTotal = (mpad - n) * 256 * 2 / 16;  // bufA pad rows in int4, 1536
    const int gPad = (padTotal + 255) / 256;         // 6

    hipMemsetAsync(gcnt, 0, (size_t)256 * CSTRIDE * 4, stream);

    k_binA<<<gEdge + gW + gPad, 256, 0, stream>>>(
        srcp, dstp, E, gcnt, bstore, W1, W2, W3, Wt,
        (int*)(bufA + (size_t)n * 256), padTotal, gEdge, gW);
    k_binB<<<nb, 256, 0, stream>>>(gcnt, bstore, cnt, col, n);

    const int gAgg = (n + 3) / 4;
    dim3 gg1(mpad / 128, 2);
    k_gemm<true><<<gg1, 256, 0, stream>>>(x, nullptr, W1t, bufB, cnt, n, 256);
    k_agg<256, 128, true, false><<<dim3(gAgg, 2), 256, 0, stream>>>(
        bufB, cnt, col, b1, bufA, nullptr, n, n);
    k_gemm<false><<<gg1, 256, 0, stream>>>(nullptr, bufA, W2t, bufB, cnt, n, 256);
    k_agg<256, 128, true, false><<<dim3(gAgg, 2), 256, 0, stream>>>(
        bufB, cnt, col, b2, bufA, nullptr, n, n);
    dim3 gg3(mpad / 128, 1);
    k_gemm<false><<<gg3, 256, 0, stream>>>(nullptr, bufA, W3t, bufB, cnt, n, 128);
    k_agg<128, 128, false, true><<<dim3(gAgg, 1), 256, 0, stream>>>(
        bufB, cnt, col, b3, nullptr, (float*)d_out, n, n);
}